// Round 18
// baseline (187.152 us; speedup 1.0000x reference)
//
#include <hip/hip_runtime.h>
#include <hip/hip_bf16.h>

typedef __attribute__((ext_vector_type(8))) short short8;
typedef __attribute__((ext_vector_type(4))) short short4v;
typedef __attribute__((ext_vector_type(4))) float f32x4;

#define MFMA16(a, b, c) __builtin_amdgcn_mfma_f32_16x16x32_bf16(a, b, c, 0, 0, 0)
#define QK_SCALE_LOG2E 0.18033688011112042f  // (1/8) * log2(e)

__device__ __forceinline__ short f2bf(float x) {
  union { float f; unsigned u; } v; v.f = x;
  unsigned u = v.u;
  u += 0x7FFFu + ((u >> 16) & 1u);  // RNE
  return (short)(u >> 16);
}
__device__ __forceinline__ short f2bf_trunc(float x) {
  union { float f; unsigned u; } v; v.f = x;
  return (short)(v.u >> 16);
}

__device__ __forceinline__ void gload16(const void* g, void* l) {
  __builtin_amdgcn_global_load_lds(
      (const __attribute__((address_space(1))) unsigned int*)g,
      (__attribute__((address_space(3))) unsigned int*)l, 16, 0, 0);
}

// ---------------------------------------------------------------------------
// Fused pre-pass: blocks [0,1728) = enc pack; [1728,4032) = wq transpose;
// [4032,6336) = wo transpose; [6336,8640) = wk/wv/wkip/wvip (576 each).
// All outputs (N x K) bf16 row-major.
// ---------------------------------------------------------------------------
__global__ __launch_bounds__(256) void prepass_kernel(
    const float* __restrict__ enc, short* __restrict__ text,
    short* __restrict__ ip,
    const float* __restrict__ wq, const float* __restrict__ wo,
    const float* __restrict__ wk, const float* __restrict__ wv,
    const float* __restrict__ wkip, const float* __restrict__ wvip,
    short* __restrict__ wqT, short* __restrict__ woT,
    short* __restrict__ wkvT, short* __restrict__ wkvipT) {
  __shared__ float tile[32][33];
  int bid = blockIdx.x;
  if (bid < 1728) {
    int i4 = bid * 256 + threadIdx.x;
    int i = i4 * 4;
    if (i >= 4 * 576 * 768) return;
    int c = i % 768;
    int rs = i / 768;
    int b = rs / 576, s = rs % 576;
    f32x4 v = *(const f32x4*)(enc + i);
    short4v o;
    o[0] = f2bf(v[0]); o[1] = f2bf(v[1]); o[2] = f2bf(v[2]); o[3] = f2bf(v[3]);
    if (s < 512)
      *(short4v*)(text + (size_t)(b * 512 + s) * 768 + c) = o;
    else
      *(short4v*)(ip + (size_t)(b * 64 + (s - 512)) * 768 + c) = o;
    return;
  }
  bid -= 1728;
  const float* src; short* dst; int N, row_off, c0, r0;
  if (bid < 2304) {
    src = wq; dst = wqT; N = 1536; row_off = 0;
    c0 = (bid % 48) * 32; r0 = (bid / 48) * 32;
  } else if (bid < 4608) {
    bid -= 2304;
    src = wo; dst = woT; N = 1536; row_off = 0;
    c0 = (bid % 48) * 32; r0 = (bid / 48) * 32;
  } else {
    bid -= 4608;
    int z = bid / 576; bid %= 576;
    N = 768;
    if (z == 0)      { src = wk;   dst = wkvT;   row_off = 0; }
    else if (z == 1) { src = wv;   dst = wkvT;   row_off = 768; }
    else if (z == 2) { src = wkip; dst = wkvipT; row_off = 0; }
    else             { src = wvip; dst = wkvipT; row_off = 768; }
    c0 = (bid % 24) * 32; r0 = (bid / 24) * 32;
  }
  int tx = threadIdx.x & 31, ty = threadIdx.x >> 5;
#pragma unroll
  for (int j = 0; j < 4; ++j)
    tile[ty + j * 8][tx] = src[(size_t)(r0 + ty + j * 8) * N + c0 + tx];
  __syncthreads();
#pragma unroll
  for (int j = 0; j < 4; ++j)
    dst[(size_t)(row_off + c0 + ty + j * 8) * N + r0 + tx] =
        f2bf(tile[tx][ty + j * 8]);
}

// ---------------------------------------------------------------------------
// 128x128-tile, BK=32, 3-buffer counted-vmcnt GEMM core.
// Swizzle f(row)=((row>>1)&3)<<4 on both sides; 48 KB LDS -> 3 blocks/CU.
// ---------------------------------------------------------------------------
__device__ __forceinline__ void stage32(const short* __restrict__ gA,
                                        const short* __restrict__ gBt,
                                        int lda, int ldb, char* buf, int tid) {
#pragma unroll
  for (int li = 0; li < 2; ++li) {
    int L = li * 4096 + tid * 16;
    int row = L >> 6;
    int cb = (L & 63) ^ (((row >> 1) & 3) << 4);
    gload16(gA + (size_t)row * lda + (cb >> 1), buf + L);
    gload16(gBt + (size_t)row * ldb + (cb >> 1), buf + 8192 + L);
  }
}

__device__ __forceinline__ void compute32(const char* p0, int wr, int wc,
                                          int lr, int hk, int xr,
                                          f32x4 acc[4][4]) {
  short8 af[4], bf[4];
#pragma unroll
  for (int m = 0; m < 4; ++m) {
    int row = wr + m * 16 + lr;
    af[m] = *(const short8*)(p0 + row * 64 + (hk ^ xr));
  }
#pragma unroll
  for (int n = 0; n < 4; ++n) {
    int row = wc + n * 16 + lr;
    bf[n] = *(const short8*)(p0 + 8192 + row * 64 + (hk ^ xr));
  }
#pragma unroll
  for (int m = 0; m < 4; ++m)
#pragma unroll
    for (int n = 0; n < 4; ++n) acc[m][n] = MFMA16(af[m], bf[n], acc[m][n]);
}

template <int K>
__device__ __forceinline__ void gemm128p(
    const short* __restrict__ A, const short* __restrict__ Bt, int lda,
    int ldb, int row0, int col0, char* sm, f32x4 acc[4][4]) {
  const int tid = threadIdx.x;
  const int lane = tid & 63, wid = tid >> 6;
  const int wr = (wid >> 1) * 64, wc = (wid & 1) * 64;
  const int lr = lane & 15;
  const int hk = (lane >> 4) * 16;
  const int xr = ((lr >> 1) & 3) << 4;
  constexpr int NT = K / 32;

  const short* gA = A + (size_t)row0 * lda;
  const short* gB = Bt + (size_t)col0 * ldb;
  char* p0 = sm;
  char* p1 = sm + 16384;
  char* p2 = sm + 32768;

  stage32(gA, gB, lda, ldb, p0, tid);
  stage32(gA + 32, gB + 32, lda, ldb, p1, tid);
  asm volatile("s_waitcnt vmcnt(4)" ::: "memory");
  __builtin_amdgcn_s_barrier();

  for (int t = 0; t < NT; ++t) {
    if (t + 2 < NT)
      stage32(gA + (t + 2) * 32, gB + (t + 2) * 32, lda, ldb, p2, tid);
    __builtin_amdgcn_sched_barrier(0);
    compute32(p0, wr, wc, lr, hk, xr, acc);
    __builtin_amdgcn_sched_barrier(0);
    if (t + 2 < NT)
      asm volatile("s_waitcnt vmcnt(4)" ::: "memory");
    else
      asm volatile("s_waitcnt vmcnt(0)" ::: "memory");
    __builtin_amdgcn_s_barrier();
    char* tmp = p0; p0 = p1; p1 = p2; p2 = tmp;
  }
}

// Row-band XCD grid mapping for 768 blocks (64 row-panels x 12 col-panels).
__device__ __forceinline__ void grid128(int bid, int& row0, int& col0) {
  int x = bid & 7;
  int j = bid >> 3;      // 0..95
  row0 = (x * 8 + (j & 7)) * 128;
  col0 = (j >> 3) * 128;
}

// ---------------------------------------------------------------------------
// Q projection body (fused f32->bf16 A-staging; see R14 ledger).
// ---------------------------------------------------------------------------
__device__ __forceinline__ void q_issueA(const float* __restrict__ gAf,
                                         int tid, f32x4 ar[4]) {
#pragma unroll
  for (int li = 0; li < 2; ++li) {
    int L = li * 4096 + tid * 16;
    int row = L >> 6;
    int cb = (L & 63) ^ (((row >> 1) & 3) << 4);
    const float* src = gAf + (size_t)row * 1536 + (cb >> 1);
    ar[li * 2] = *(const f32x4*)src;
    ar[li * 2 + 1] = *(const f32x4*)(src + 4);
  }
}
__device__ __forceinline__ void q_writeA(char* buf, int tid, const f32x4 ar[4]) {
#pragma unroll
  for (int li = 0; li < 2; ++li) {
    int L = li * 4096 + tid * 16;
    short8 s;
#pragma unroll
    for (int j = 0; j < 4; ++j) {
      s[j] = f2bf_trunc(ar[li * 2][j]);
      s[j + 4] = f2bf_trunc(ar[li * 2 + 1][j]);
    }
    *(short8*)(buf + L) = s;
  }
}
__device__ __forceinline__ void q_stageB(const short* __restrict__ gBt,
                                         char* buf, int tid) {
#pragma unroll
  for (int li = 0; li < 2; ++li) {
    int L = li * 4096 + tid * 16;
    int row = L >> 6;
    int cb = (L & 63) ^ (((row >> 1) & 3) << 4);
    gload16(gBt + (size_t)row * 1536 + (cb >> 1), buf + 8192 + L);
  }
}

__device__ void q_proj_body(int bid, const float* __restrict__ hs,
                            const short* __restrict__ wqT,
                            const float* __restrict__ rc,
                            const float* __restrict__ rsn,
                            short* __restrict__ qbuf, char* sm) {
  f32x4 acc[4][4] = {};
  int row0, col0;
  grid128(bid, row0, col0);

  const int tid = threadIdx.x;
  const int lane = tid & 63, wid = tid >> 6;
  const int wr = (wid >> 1) * 64, wc = (wid & 1) * 64;
  const int lr = lane & 15;
  const int hk = (lane >> 4) * 16;
  const int xr = ((lr >> 1) & 3) << 4;
  constexpr int NT = 48;

  const float* gAf = hs + (size_t)row0 * 1536;
  const short* gB = wqT + (size_t)col0 * 1536;
  char* p0 = sm;
  char* p1 = sm + 16384;
  char* p2 = sm + 32768;
  f32x4 arA[4], arB[4];

  q_issueA(gAf, tid, arA);
  q_stageB(gB, p0, tid);
  q_issueA(gAf + 32, tid, arB);
  q_stageB(gB + 32, p1, tid);
  asm volatile("s_waitcnt vmcnt(8)" ::: "memory");  // A0 landed
  q_writeA(p0, tid, arA);
  asm volatile("s_waitcnt vmcnt(6) lgkmcnt(0)" ::: "memory");  // B0 + write vis
  __builtin_amdgcn_s_barrier();

  for (int t = 0; t < NT; ++t) {
    if (t + 2 < NT) {
      if ((t & 1) == 0) q_issueA(gAf + (t + 2) * 32, tid, arA);
      else              q_issueA(gAf + (t + 2) * 32, tid, arB);
      q_stageB(gB + (t + 2) * 32, p2, tid);
    }
    __builtin_amdgcn_sched_barrier(0);
    compute32(p0, wr, wc, lr, hk, xr, acc);
    __builtin_amdgcn_sched_barrier(0);
    if (t + 2 < NT)
      asm volatile("s_waitcnt vmcnt(6)" ::: "memory");  // A(t+1),B(t+1) landed
    else
      asm volatile("s_waitcnt vmcnt(0)" ::: "memory");
    if (t + 1 < NT) {
      if ((t & 1) == 0) q_writeA(p1, tid, arB);
      else              q_writeA(p1, tid, arA);
    }
    asm volatile("s_waitcnt lgkmcnt(0)" ::: "memory");
    __builtin_amdgcn_s_barrier();
    char* tmp = p0; p0 = p1; p1 = p2; p2 = tmp;
  }

  const int lrow4 = (lane >> 4) * 4;
  const int h = (col0 + wc) >> 6;
#pragma unroll
  for (int m = 0; m < 4; ++m) {
#pragma unroll
    for (int r = 0; r < 4; ++r) {
      int grow = row0 + wr + m * 16 + lrow4 + r;
      int b = grow >> 11, t = grow & 2047;
      float v0 = acc[m][0][r], v1 = acc[m][1][r];
      float c0 = rc[t * 32 + lr], s0 = rsn[t * 32 + lr];
      float c1 = rc[t * 32 + 16 + lr], s1 = rsn[t * 32 + 16 + lr];
      float n0 = (v0 * c0 - v1 * s0) * QK_SCALE_LOG2E;
      float n1 = (v1 * c1 + v0 * s1) * QK_SCALE_LOG2E;
      short* ob = qbuf + ((size_t)(b * 24 + h) * 2048 + t) * 64;
      ob[lr] = f2bf(n0);
      ob[16 + lr] = f2bf(n1);
      ob[32 + lr] = f2bf(acc[m][2][r] * QK_SCALE_LOG2E);
      ob[48 + lr] = f2bf(acc[m][3][r] * QK_SCALE_LOG2E);
    }
  }
}

// ---------------------------------------------------------------------------
// KV body (text cols<768 -> K layout; cols>=768 -> permuted V^T layout).
// ---------------------------------------------------------------------------
__device__ void kv_body(int bx, int by, const short* __restrict__ textbf,
                        const short* __restrict__ ipbf,
                        const short* __restrict__ wkvT,
                        const short* __restrict__ wkvipT,
                        short* __restrict__ kbuf, short* __restrict__ vtbuf,
                        short* __restrict__ kipbuf,
                        short* __restrict__ vtipbuf, char* sm) {
  f32x4 acc[4][4] = {};
  const bool ip = by >= 16;
  const short* Abf = ip ? ipbf : textbf;
  const short* W = ip ? wkvipT : wkvT;
  short* kout = ip ? kipbuf : kbuf;
  short* vtout = ip ? vtipbuf : vtbuf;
  const int rlog2 = ip ? 6 : 9;
  const int row0 = (ip ? (by - 16) : by) * 128;
  const int col0 = bx * 128;
  gemm128p<768>(Abf, W, 768, 768, row0, col0, sm, acc);

  const int tid = threadIdx.x;
  const int lane = tid & 63, wid = tid >> 6;
  const int wr = (wid >> 1) * 64, wc = (wid & 1) * 64;
  const int lr = lane & 15, lrow4 = (lane >> 4) * 4;
  const int rmask = (1 << rlog2) - 1;
#pragma unroll
  for (int m = 0; m < 4; ++m) {
#pragma unroll
    for (int n = 0; n < 4; ++n) {
#pragma unroll
      for (int r = 0; r < 4; ++r) {
        int grow = row0 + wr + m * 16 + lrow4 + r;
        int gcol = col0 + wc + n * 16 + lr;
        int b = grow >> rlog2, key = grow & rmask;
        short val = f2bf(acc[m][n][r]);
        if (gcol < 768) {
          int kvh = gcol >> 6, d = gcol & 63;
          kout[((((size_t)(b * 12 + kvh)) << rlog2) + key) * 64 + d] = val;
        } else {
          int c2 = gcol - 768;
          int kvh = c2 >> 6, d = c2 & 63;
          int kp = (key & ~31) | (((key >> 2) & 3) << 3) |
                   (((key >> 4) & 1) << 2) | (key & 3);
          vtout[(((size_t)((b * 12 + kvh) * 64 + d)) << rlog2) + kp] = val;
        }
      }
    }
  }
}

// Combined launch, KV FIRST so its 216 blocks co-reside with the first wave
// of q blocks (fills q's latency stalls) instead of forming an idle tail:
// blocks 0..215 kv (12 x 18), 216..983 q_proj.
__global__ __launch_bounds__(256, 3) void qkv_kernel(
    const float* __restrict__ hs, const short* __restrict__ wqT,
    const float* __restrict__ rc, const float* __restrict__ rsn,
    short* __restrict__ qbuf, const short* __restrict__ textbf,
    const short* __restrict__ ipbf, const short* __restrict__ wkvT,
    const short* __restrict__ wkvipT, short* __restrict__ kbuf,
    short* __restrict__ vtbuf, short* __restrict__ kipbuf,
    short* __restrict__ vtipbuf) {
  __shared__ char sm[49152];
  if (blockIdx.x < 216) {
    kv_body(blockIdx.x % 12, blockIdx.x / 12, textbf, ipbf, wkvT, wkvipT,
            kbuf, vtbuf, kipbuf, vtipbuf, sm);
  } else {
    q_proj_body(blockIdx.x - 216, hs, wqT, rc, rsn, qbuf, sm);
  }
}

// ---------------------------------------------------------------------------
// Output projection: 3-buffer LDS core + plain bias/resid epilogue.
// ---------------------------------------------------------------------------
__global__ __launch_bounds__(256, 3) void o_proj_128p(
    const short* __restrict__ attnbf, const short* __restrict__ woT,
    const float* __restrict__ bo, const float* __restrict__ resid,
    float* __restrict__ out) {
  __shared__ char sm[49152];
  f32x4 acc[4][4] = {};
  int row0, col0;
  grid128(blockIdx.x, row0, col0);
  gemm128p<1536>(attnbf, woT, 1536, 1536, row0, col0, sm, acc);

  const int lane = threadIdx.x & 63, wid = threadIdx.x >> 6;
  const int wr = (wid >> 1) * 64, wc = (wid & 1) * 64;
  const int lr = lane & 15, lrow4 = (lane >> 4) * 4;
#pragma unroll
  for (int m = 0; m < 4; ++m) {
#pragma unroll
    for (int n = 0; n < 4; ++n) {
#pragma unroll
      for (int r = 0; r < 4; ++r) {
        int grow = row0 + wr + m * 16 + lrow4 + r;
        int gcol = col0 + wc + n * 16 + lr;
        size_t off = (size_t)grow * 1536 + gcol;
        out[off] = acc[m][n][r] + bo[gcol] + resid[off];
      }
    }
  }
}

// ---------------------------------------------------------------------------
// Attention: swapped QK^T, in-register P, per-lane deferred max, 3-buffer
// counted-vmcnt K/V pipeline.
// ---------------------------------------------------------------------------
__device__ __forceinline__ void stage_tile(const short* __restrict__ ks,
                                           const short* __restrict__ vs,
                                           int vstr, short* kb, short* vb,
                                           int tid) {
#pragma unroll
  for (int q = 0; q < 2; ++q) {
    int L = q * 4096 + tid * 16;
    int row = L >> 7;
    int sc = ((L & 127) ^ ((row & 7) << 4)) >> 1;
    gload16(ks + row * 64 + sc, (char*)kb + L);
    gload16(vs + (size_t)row * vstr + sc, (char*)vb + L);
  }
}

__device__ __forceinline__ void attn_tile(const short* kb, const short* vb,
                                          const short8 qf[2],
                                          float& m_run, float& l_run,
                                          f32x4 o_acc[4], int lane) {
  const int lr = lane & 15, hi = lane >> 4;
  f32x4 s[4];
#pragma unroll
  for (int nf = 0; nf < 4; ++nf) {
    int row = nf * 16 + lr;
    int rx = (row & 7) << 4;
    const char* base = (const char*)kb + row * 128;
    short8 k0 = *(const short8*)(base + ((hi * 16) ^ rx));
    short8 k1 = *(const short8*)(base + ((64 + hi * 16) ^ rx));
    f32x4 a = {0.f, 0.f, 0.f, 0.f};
    a = MFMA16(k0, qf[0], a);
    a = MFMA16(k1, qf[1], a);
    s[nf] = a;
  }
  float mx = fmaxf(fmaxf(s[0][0], s[0][1]), fmaxf(s[0][2], s[0][3]));
#pragma unroll
  for (int nf = 1; nf < 4; ++nf)
    mx = fmaxf(mx, fmaxf(fmaxf(s[nf][0], s[nf][1]), fmaxf(s[nf][2], s[nf][3])));
  if (__any(mx - m_run > 8.0f)) {
    float mr = fmaxf(mx, __shfl_xor(mx, 16));
    mr = fmaxf(mr, __shfl_xor(mr, 32));
    float mn = fmaxf(m_run, mr);
    float corr = __builtin_amdgcn_exp2f(m_run - mn);
    m_run = mn;
    l_run *= corr;
#pragma unroll
    for (int r = 0; r < 4; ++r) {
      float cr = __shfl(corr, hi * 4 + r);
#pragma unroll
      for (int no = 0; no < 4; ++no) o_acc[no][r] *= cr;
    }
  }
  short8 pa[2];
#pragma unroll
  for (int nf = 0; nf < 4; ++nf) {
#pragma unroll
    for (int r = 0; r < 4; ++r) {
      float p = __builtin_amdgcn_exp2f(s[nf][r] - m_run);
      l_run += p;
      pa[nf >> 1][(nf & 1) * 4 + r] = f2bf_trunc(p);
    }
  }
#pragma unroll
  for (int ks = 0; ks < 2; ++ks) {
#pragma unroll
    for (int no = 0; no < 4; ++no) {
      int row = no * 16 + lr;
      int rx = (row & 7) << 4;
      short8 vf = *(const short8*)((const char*)vb + row * 128 +
                                   ((ks * 64 + hi * 16) ^ rx));
      o_acc[no] = MFMA16(pa[ks], vf, o_acc[no]);
    }
  }
}

__global__ __launch_bounds__(256, 3) void attn_kernel(
    const short* __restrict__ qbuf, const short* __restrict__ kbuf,
    const short* __restrict__ vtbuf, const short* __restrict__ kipbuf,
    const short* __restrict__ vtipbuf, short* __restrict__ attn_out) {
  const int tid = threadIdx.x;
  const int lane = tid & 63, wid = tid >> 6;
  const int f = (blockIdx.x & 7) * 384 + (blockIdx.x >> 3);
  const int qt = f & 31;
  const int h = (f >> 5) % 24;
  const int b = f / (32 * 24);
  const int kvh = h >> 1;
  const int lr = lane & 15, hi = lane >> 4;

  __shared__ short skv_k[3 * 64 * 64];
  __shared__ short skv_v[3 * 64 * 64];

  const short* qp = qbuf + (size_t)(b * 24 + h) * 2048 * 64;
  const short* kp = kbuf + (size_t)(b * 12 + kvh) * 512 * 64;
  const short* vp = vtbuf + (size_t)(b * 12 + kvh) * 64 * 512;
  const short* kip = kipbuf + (size_t)(b * 12 + kvh) * 64 * 64;
  const short* vip = vtipbuf + (size_t)(b * 12 + kvh) * 64 * 64;

  const int q0 = qt * 64 + wid * 16;
  short8 qf[2];
  qf[0] = *(const short8*)(qp + (size_t)(q0 + lr) * 64 + hi * 8);
  qf[1] = *(const short8*)(qp + (size_t)(q0 + lr) * 64 + 32 + hi * 8);

  float m1 = -1.0e30f, l1 = 0.f, m2 = -1.0e30f, l2 = 0.f;
  f32x4 oacc1[4] = {}, oacc2[4] = {};

  stage_tile(kp, vp, 512, skv_k, skv_v, tid);
  stage_tile(kp + 64 * 64, vp + 64, 512, skv_k + 4096, skv_v + 4096, tid);
  asm volatile("s_waitcnt vmcnt(4)" ::: "memory");
  __builtin_amdgcn_s_barrier();

  for (int t = 0; t < 9; ++t) {
    if (t + 2 <= 8) {
      int tt = t + 2;
      const short* ks_ = (tt < 8) ? kp + tt * 64 * 64 : kip;
      const short* vs_ = (tt < 8) ? vp + tt * 64 : vip;
      int vstr = (tt < 8) ? 512 : 64;
      int bsel = tt % 3;
      stage_tile(ks_, vs_, vstr, skv_k + bsel * 4096, skv_v + bsel * 4096, tid);
    }
    __builtin_amdgcn_sched_barrier(0);
    int cur = t % 3;
    if (t < 8)
      attn_tile(skv_k + cur * 4096, skv_v + cur * 4096, qf, m1, l1, oacc1, lane);
    else
      attn_tile(skv_k + cur * 4096, skv_v + cur * 4096, qf, m2, l2, oacc2, lane);
    __builtin_amdgcn_sched_barrier(0);
    if (t + 2 <= 8)
      asm volatile("s_waitcnt vmcnt(4)" ::: "memory");
    else if (t + 1 <= 8)
      asm volatile("s_waitcnt vmcnt(0)" ::: "memory");
    __builtin_amdgcn_s_barrier();
  }

  l1 += __shfl_xor(l1, 16); l1 += __shfl_xor(l1, 32);
  l2 += __shfl_xor(l2, 16); l2 += __shfl_xor(l2, 32);
  float inv1 = 1.0f / l1, inv2 = 1.0f / l2;
#pragma unroll
  for (int r = 0; r < 4; ++r) {
    float i1 = __shfl(inv1, hi * 4 + r);
    float i2 = __shfl(inv2, hi * 4 + r);
    int grow = b * 2048 + q0 + hi * 4 + r;
#pragma unroll
    for (int no = 0; no < 4; ++no) {
      float val = oacc1[no][r] * i1 + oacc2[no][r] * i2;
      attn_out[(size_t)grow * 1536 + h * 64 + no * 16 + lr] = f2bf(val);
    }
  }
}

// ---------------------------------------------------------------------------
extern "C" void kernel_launch(void* const* d_in, const int* in_sizes, int n_in,
                              void* d_out, int out_size, void* d_ws, size_t ws_size,
                              hipStream_t stream) {
  const float* hs = (const float*)d_in[0];
  const float* enc = (const float*)d_in[1];
  const float* rc = (const float*)d_in[2];
  const float* rsn = (const float*)d_in[3];
  const float* wq = (const float*)d_in[4];
  const float* wk = (const float*)d_in[5];
  const float* wv = (const float*)d_in[6];
  const float* wkip = (const float*)d_in[7];
  const float* wvip = (const float*)d_in[8];
  const float* wo = (const float*)d_in[9];
  const float* bo = (const float*)d_in[10];
  float* out = (float*)d_out;

  char* ws = (char*)d_ws;
  short* attnbuf = (short*)(ws + 0);          // 25165824
  short* qbuf    = (short*)(ws + 25165824);   // 25165824
  short* kbuf    = (short*)(ws + 50331648);   //  3145728
  short* vtbuf   = (short*)(ws + 53477376);   //  3145728
  short* kipbuf  = (short*)(ws + 56623104);   //   393216
  short* vtipbuf = (short*)(ws + 57016320);   //   393216
  short* textbf  = (short*)(ws + 57409536);   //  3145728
  short* ipbf    = (short*)(ws + 60555264);   //   393216
  short* wqT     = (short*)(ws + 60948480);   //  4718592
  short* woT     = (short*)(ws + 65667072);   //  4718592
  short* wkvT    = (short*)(ws + 70385664);   //  2359296
  short* wkvipT  = (short*)(ws + 72744960);   //  2359296
  // total 75104256 bytes

  // --- fused pre-pass: enc pack + all weight transposes ---
  prepass_kernel<<<8640, 256, 0, stream>>>(enc, textbf, ipbf, wq, wo, wk, wv,
                                           wkip, wvip, wqT, woT, wkvT, wkvipT);

  // --- fused K/V + Q projections (kv blocks first) ---
  qkv_kernel<<<984, 256, 0, stream>>>(hs, wqT, rc, rsn, qbuf, textbf, ipbf,
                                      wkvT, wkvipT, kbuf, vtbuf, kipbuf,
                                      vtipbuf);

  // --- attention ---
  attn_kernel<<<3072, 256, 0, stream>>>(qbuf, kbuf, vtbuf, kipbuf,
                                        vtipbuf, attnbuf);

  // --- output projection + bias + residual ---
  o_proj_128p<<<768, 256, 0, stream>>>(attnbuf, woT, bo, hs, out);
}

// Round 19
// 178.403 us; speedup vs baseline: 1.0490x; 1.0490x over previous
//
#include <hip/hip_runtime.h>
#include <hip/hip_bf16.h>

typedef __attribute__((ext_vector_type(8))) short short8;
typedef __attribute__((ext_vector_type(4))) short short4v;
typedef __attribute__((ext_vector_type(4))) float f32x4;

#define MFMA16(a, b, c) __builtin_amdgcn_mfma_f32_16x16x32_bf16(a, b, c, 0, 0, 0)
#define QK_SCALE_LOG2E 0.18033688011112042f  // (1/8) * log2(e)

__device__ __forceinline__ short f2bf(float x) {
  union { float f; unsigned u; } v; v.f = x;
  unsigned u = v.u;
  u += 0x7FFFu + ((u >> 16) & 1u);  // RNE
  return (short)(u >> 16);
}
__device__ __forceinline__ short f2bf_trunc(float x) {
  union { float f; unsigned u; } v; v.f = x;
  return (short)(v.u >> 16);
}

__device__ __forceinline__ void gload16(const void* g, void* l) {
  __builtin_amdgcn_global_load_lds(
      (const __attribute__((address_space(1))) unsigned int*)g,
      (__attribute__((address_space(3))) unsigned int*)l, 16, 0, 0);
}

// ---------------------------------------------------------------------------
// Fused pre-pass: blocks [0,1728) = enc pack; [1728,4032) = wq transpose;
// [4032,6336) = wo transpose; [6336,8640) = wk/wv/wkip/wvip (576 each).
// All outputs (N x K) bf16 row-major.
// ---------------------------------------------------------------------------
__global__ __launch_bounds__(256) void prepass_kernel(
    const float* __restrict__ enc, short* __restrict__ text,
    short* __restrict__ ip,
    const float* __restrict__ wq, const float* __restrict__ wo,
    const float* __restrict__ wk, const float* __restrict__ wv,
    const float* __restrict__ wkip, const float* __restrict__ wvip,
    short* __restrict__ wqT, short* __restrict__ woT,
    short* __restrict__ wkvT, short* __restrict__ wkvipT) {
  __shared__ float tile[32][33];
  int bid = blockIdx.x;
  if (bid < 1728) {
    int i4 = bid * 256 + threadIdx.x;
    int i = i4 * 4;
    if (i >= 4 * 576 * 768) return;
    int c = i % 768;
    int rs = i / 768;
    int b = rs / 576, s = rs % 576;
    f32x4 v = *(const f32x4*)(enc + i);
    short4v o;
    o[0] = f2bf(v[0]); o[1] = f2bf(v[1]); o[2] = f2bf(v[2]); o[3] = f2bf(v[3]);
    if (s < 512)
      *(short4v*)(text + (size_t)(b * 512 + s) * 768 + c) = o;
    else
      *(short4v*)(ip + (size_t)(b * 64 + (s - 512)) * 768 + c) = o;
    return;
  }
  bid -= 1728;
  const float* src; short* dst; int N, row_off, c0, r0;
  if (bid < 2304) {
    src = wq; dst = wqT; N = 1536; row_off = 0;
    c0 = (bid % 48) * 32; r0 = (bid / 48) * 32;
  } else if (bid < 4608) {
    bid -= 2304;
    src = wo; dst = woT; N = 1536; row_off = 0;
    c0 = (bid % 48) * 32; r0 = (bid / 48) * 32;
  } else {
    bid -= 4608;
    int z = bid / 576; bid %= 576;
    N = 768;
    if (z == 0)      { src = wk;   dst = wkvT;   row_off = 0; }
    else if (z == 1) { src = wv;   dst = wkvT;   row_off = 768; }
    else if (z == 2) { src = wkip; dst = wkvipT; row_off = 0; }
    else             { src = wvip; dst = wkvipT; row_off = 768; }
    c0 = (bid % 24) * 32; r0 = (bid / 24) * 32;
  }
  int tx = threadIdx.x & 31, ty = threadIdx.x >> 5;
#pragma unroll
  for (int j = 0; j < 4; ++j)
    tile[ty + j * 8][tx] = src[(size_t)(r0 + ty + j * 8) * N + c0 + tx];
  __syncthreads();
#pragma unroll
  for (int j = 0; j < 4; ++j)
    dst[(size_t)(row_off + c0 + ty + j * 8) * N + r0 + tx] =
        f2bf(tile[tx][ty + j * 8]);
}

// ---------------------------------------------------------------------------
// 128x128-tile, BK=32, 3-buffer counted-vmcnt GEMM core.
// Swizzle f(row)=((row>>1)&3)<<4 on both sides; 48 KB LDS -> 3 blocks/CU.
// ---------------------------------------------------------------------------
__device__ __forceinline__ void stage32(const short* __restrict__ gA,
                                        const short* __restrict__ gBt,
                                        int lda, int ldb, char* buf, int tid) {
#pragma unroll
  for (int li = 0; li < 2; ++li) {
    int L = li * 4096 + tid * 16;
    int row = L >> 6;
    int cb = (L & 63) ^ (((row >> 1) & 3) << 4);
    gload16(gA + (size_t)row * lda + (cb >> 1), buf + L);
    gload16(gBt + (size_t)row * ldb + (cb >> 1), buf + 8192 + L);
  }
}

__device__ __forceinline__ void compute32(const char* p0, int wr, int wc,
                                          int lr, int hk, int xr,
                                          f32x4 acc[4][4]) {
  short8 af[4], bf[4];
#pragma unroll
  for (int m = 0; m < 4; ++m) {
    int row = wr + m * 16 + lr;
    af[m] = *(const short8*)(p0 + row * 64 + (hk ^ xr));
  }
#pragma unroll
  for (int n = 0; n < 4; ++n) {
    int row = wc + n * 16 + lr;
    bf[n] = *(const short8*)(p0 + 8192 + row * 64 + (hk ^ xr));
  }
#pragma unroll
  for (int m = 0; m < 4; ++m)
#pragma unroll
    for (int n = 0; n < 4; ++n) acc[m][n] = MFMA16(af[m], bf[n], acc[m][n]);
}

template <int K>
__device__ __forceinline__ void gemm128p(
    const short* __restrict__ A, const short* __restrict__ Bt, int lda,
    int ldb, int row0, int col0, char* sm, f32x4 acc[4][4]) {
  const int tid = threadIdx.x;
  const int lane = tid & 63, wid = tid >> 6;
  const int wr = (wid >> 1) * 64, wc = (wid & 1) * 64;
  const int lr = lane & 15;
  const int hk = (lane >> 4) * 16;
  const int xr = ((lr >> 1) & 3) << 4;
  constexpr int NT = K / 32;

  const short* gA = A + (size_t)row0 * lda;
  const short* gB = Bt + (size_t)col0 * ldb;
  char* p0 = sm;
  char* p1 = sm + 16384;
  char* p2 = sm + 32768;

  stage32(gA, gB, lda, ldb, p0, tid);
  stage32(gA + 32, gB + 32, lda, ldb, p1, tid);
  asm volatile("s_waitcnt vmcnt(4)" ::: "memory");
  __builtin_amdgcn_s_barrier();

  for (int t = 0; t < NT; ++t) {
    if (t + 2 < NT)
      stage32(gA + (t + 2) * 32, gB + (t + 2) * 32, lda, ldb, p2, tid);
    __builtin_amdgcn_sched_barrier(0);
    compute32(p0, wr, wc, lr, hk, xr, acc);
    __builtin_amdgcn_sched_barrier(0);
    if (t + 2 < NT)
      asm volatile("s_waitcnt vmcnt(4)" ::: "memory");
    else
      asm volatile("s_waitcnt vmcnt(0)" ::: "memory");
    __builtin_amdgcn_s_barrier();
    char* tmp = p0; p0 = p1; p1 = p2; p2 = tmp;
  }
}

// Row-band XCD grid mapping for 768 blocks (64 row-panels x 12 col-panels).
__device__ __forceinline__ void grid128(int bid, int& row0, int& col0) {
  int x = bid & 7;
  int j = bid >> 3;      // 0..95
  row0 = (x * 8 + (j & 7)) * 128;
  col0 = (j >> 3) * 128;
}

// ---------------------------------------------------------------------------
// Q projection body (fused f32->bf16 A-staging; see R14 ledger).
// ---------------------------------------------------------------------------
__device__ __forceinline__ void q_issueA(const float* __restrict__ gAf,
                                         int tid, f32x4 ar[4]) {
#pragma unroll
  for (int li = 0; li < 2; ++li) {
    int L = li * 4096 + tid * 16;
    int row = L >> 6;
    int cb = (L & 63) ^ (((row >> 1) & 3) << 4);
    const float* src = gAf + (size_t)row * 1536 + (cb >> 1);
    ar[li * 2] = *(const f32x4*)src;
    ar[li * 2 + 1] = *(const f32x4*)(src + 4);
  }
}
__device__ __forceinline__ void q_writeA(char* buf, int tid, const f32x4 ar[4]) {
#pragma unroll
  for (int li = 0; li < 2; ++li) {
    int L = li * 4096 + tid * 16;
    short8 s;
#pragma unroll
    for (int j = 0; j < 4; ++j) {
      s[j] = f2bf_trunc(ar[li * 2][j]);
      s[j + 4] = f2bf_trunc(ar[li * 2 + 1][j]);
    }
    *(short8*)(buf + L) = s;
  }
}
__device__ __forceinline__ void q_stageB(const short* __restrict__ gBt,
                                         char* buf, int tid) {
#pragma unroll
  for (int li = 0; li < 2; ++li) {
    int L = li * 4096 + tid * 16;
    int row = L >> 6;
    int cb = (L & 63) ^ (((row >> 1) & 3) << 4);
    gload16(gBt + (size_t)row * 1536 + (cb >> 1), buf + 8192 + L);
  }
}

__device__ void q_proj_body(int bid, const float* __restrict__ hs,
                            const short* __restrict__ wqT,
                            const float* __restrict__ rc,
                            const float* __restrict__ rsn,
                            short* __restrict__ qbuf, char* sm) {
  f32x4 acc[4][4] = {};
  int row0, col0;
  grid128(bid, row0, col0);

  const int tid = threadIdx.x;
  const int lane = tid & 63, wid = tid >> 6;
  const int wr = (wid >> 1) * 64, wc = (wid & 1) * 64;
  const int lr = lane & 15;
  const int hk = (lane >> 4) * 16;
  const int xr = ((lr >> 1) & 3) << 4;
  constexpr int NT = 48;

  const float* gAf = hs + (size_t)row0 * 1536;
  const short* gB = wqT + (size_t)col0 * 1536;
  char* p0 = sm;
  char* p1 = sm + 16384;
  char* p2 = sm + 32768;
  f32x4 arA[4], arB[4];

  q_issueA(gAf, tid, arA);
  q_stageB(gB, p0, tid);
  q_issueA(gAf + 32, tid, arB);
  q_stageB(gB + 32, p1, tid);
  asm volatile("s_waitcnt vmcnt(8)" ::: "memory");  // A0 landed
  q_writeA(p0, tid, arA);
  asm volatile("s_waitcnt vmcnt(6) lgkmcnt(0)" ::: "memory");  // B0 + write vis
  __builtin_amdgcn_s_barrier();

  for (int t = 0; t < NT; ++t) {
    if (t + 2 < NT) {
      if ((t & 1) == 0) q_issueA(gAf + (t + 2) * 32, tid, arA);
      else              q_issueA(gAf + (t + 2) * 32, tid, arB);
      q_stageB(gB + (t + 2) * 32, p2, tid);
    }
    __builtin_amdgcn_sched_barrier(0);
    compute32(p0, wr, wc, lr, hk, xr, acc);
    __builtin_amdgcn_sched_barrier(0);
    if (t + 2 < NT)
      asm volatile("s_waitcnt vmcnt(6)" ::: "memory");  // A(t+1),B(t+1) landed
    else
      asm volatile("s_waitcnt vmcnt(0)" ::: "memory");
    if (t + 1 < NT) {
      if ((t & 1) == 0) q_writeA(p1, tid, arB);
      else              q_writeA(p1, tid, arA);
    }
    asm volatile("s_waitcnt lgkmcnt(0)" ::: "memory");
    __builtin_amdgcn_s_barrier();
    char* tmp = p0; p0 = p1; p1 = p2; p2 = tmp;
  }

  const int lrow4 = (lane >> 4) * 4;
  const int h = (col0 + wc) >> 6;
#pragma unroll
  for (int m = 0; m < 4; ++m) {
#pragma unroll
    for (int r = 0; r < 4; ++r) {
      int grow = row0 + wr + m * 16 + lrow4 + r;
      int b = grow >> 11, t = grow & 2047;
      float v0 = acc[m][0][r], v1 = acc[m][1][r];
      float c0 = rc[t * 32 + lr], s0 = rsn[t * 32 + lr];
      float c1 = rc[t * 32 + 16 + lr], s1 = rsn[t * 32 + 16 + lr];
      float n0 = (v0 * c0 - v1 * s0) * QK_SCALE_LOG2E;
      float n1 = (v1 * c1 + v0 * s1) * QK_SCALE_LOG2E;
      short* ob = qbuf + ((size_t)(b * 24 + h) * 2048 + t) * 64;
      ob[lr] = f2bf(n0);
      ob[16 + lr] = f2bf(n1);
      ob[32 + lr] = f2bf(acc[m][2][r] * QK_SCALE_LOG2E);
      ob[48 + lr] = f2bf(acc[m][3][r] * QK_SCALE_LOG2E);
    }
  }
}

// ---------------------------------------------------------------------------
// KV body (text cols<768 -> K layout; cols>=768 -> permuted V^T layout).
// ---------------------------------------------------------------------------
__device__ void kv_body(int bx, int by, const short* __restrict__ textbf,
                        const short* __restrict__ ipbf,
                        const short* __restrict__ wkvT,
                        const short* __restrict__ wkvipT,
                        short* __restrict__ kbuf, short* __restrict__ vtbuf,
                        short* __restrict__ kipbuf,
                        short* __restrict__ vtipbuf, char* sm) {
  f32x4 acc[4][4] = {};
  const bool ip = by >= 16;
  const short* Abf = ip ? ipbf : textbf;
  const short* W = ip ? wkvipT : wkvT;
  short* kout = ip ? kipbuf : kbuf;
  short* vtout = ip ? vtipbuf : vtbuf;
  const int rlog2 = ip ? 6 : 9;
  const int row0 = (ip ? (by - 16) : by) * 128;
  const int col0 = bx * 128;
  gemm128p<768>(Abf, W, 768, 768, row0, col0, sm, acc);

  const int tid = threadIdx.x;
  const int lane = tid & 63, wid = tid >> 6;
  const int wr = (wid >> 1) * 64, wc = (wid & 1) * 64;
  const int lr = lane & 15, lrow4 = (lane >> 4) * 4;
  const int rmask = (1 << rlog2) - 1;
#pragma unroll
  for (int m = 0; m < 4; ++m) {
#pragma unroll
    for (int n = 0; n < 4; ++n) {
#pragma unroll
      for (int r = 0; r < 4; ++r) {
        int grow = row0 + wr + m * 16 + lrow4 + r;
        int gcol = col0 + wc + n * 16 + lr;
        int b = grow >> rlog2, key = grow & rmask;
        short val = f2bf(acc[m][n][r]);
        if (gcol < 768) {
          int kvh = gcol >> 6, d = gcol & 63;
          kout[((((size_t)(b * 12 + kvh)) << rlog2) + key) * 64 + d] = val;
        } else {
          int c2 = gcol - 768;
          int kvh = c2 >> 6, d = c2 & 63;
          int kp = (key & ~31) | (((key >> 2) & 3) << 3) |
                   (((key >> 4) & 1) << 2) | (key & 3);
          vtout[(((size_t)((b * 12 + kvh) * 64 + d)) << rlog2) + kp] = val;
        }
      }
    }
  }
}

// Combined q_proj + kv launch: blocks 0..767 q, 768..983 kv (12 x 18).
// (q first: preserves q's XCD row-band L2 locality — kv-first polluted L2,
//  FETCH 63->87 MB and total regressed; measured R17 vs R18.)
__global__ __launch_bounds__(256, 3) void qkv_kernel(
    const float* __restrict__ hs, const short* __restrict__ wqT,
    const float* __restrict__ rc, const float* __restrict__ rsn,
    short* __restrict__ qbuf, const short* __restrict__ textbf,
    const short* __restrict__ ipbf, const short* __restrict__ wkvT,
    const short* __restrict__ wkvipT, short* __restrict__ kbuf,
    short* __restrict__ vtbuf, short* __restrict__ kipbuf,
    short* __restrict__ vtipbuf) {
  __shared__ char sm[49152];
  if (blockIdx.x < 768) {
    q_proj_body(blockIdx.x, hs, wqT, rc, rsn, qbuf, sm);
  } else {
    int bid = blockIdx.x - 768;
    kv_body(bid % 12, bid / 12, textbf, ipbf, wkvT, wkvipT, kbuf, vtbuf,
            kipbuf, vtipbuf, sm);
  }
}

// ---------------------------------------------------------------------------
// Output projection: 3-buffer LDS core + plain bias/resid epilogue.
// ---------------------------------------------------------------------------
__global__ __launch_bounds__(256, 3) void o_proj_128p(
    const short* __restrict__ attnbf, const short* __restrict__ woT,
    const float* __restrict__ bo, const float* __restrict__ resid,
    float* __restrict__ out) {
  __shared__ char sm[49152];
  f32x4 acc[4][4] = {};
  int row0, col0;
  grid128(blockIdx.x, row0, col0);
  gemm128p<1536>(attnbf, woT, 1536, 1536, row0, col0, sm, acc);

  const int lane = threadIdx.x & 63, wid = threadIdx.x >> 6;
  const int wr = (wid >> 1) * 64, wc = (wid & 1) * 64;
  const int lr = lane & 15, lrow4 = (lane >> 4) * 4;
#pragma unroll
  for (int m = 0; m < 4; ++m) {
#pragma unroll
    for (int n = 0; n < 4; ++n) {
#pragma unroll
      for (int r = 0; r < 4; ++r) {
        int grow = row0 + wr + m * 16 + lrow4 + r;
        int gcol = col0 + wc + n * 16 + lr;
        size_t off = (size_t)grow * 1536 + gcol;
        out[off] = acc[m][n][r] + bo[gcol] + resid[off];
      }
    }
  }
}

// ---------------------------------------------------------------------------
// Attention: swapped QK^T, in-register P, per-lane deferred max, 3-buffer
// counted-vmcnt K/V pipeline.
// ---------------------------------------------------------------------------
__device__ __forceinline__ void stage_tile(const short* __restrict__ ks,
                                           const short* __restrict__ vs,
                                           int vstr, short* kb, short* vb,
                                           int tid) {
#pragma unroll
  for (int q = 0; q < 2; ++q) {
    int L = q * 4096 + tid * 16;
    int row = L >> 7;
    int sc = ((L & 127) ^ ((row & 7) << 4)) >> 1;
    gload16(ks + row * 64 + sc, (char*)kb + L);
    gload16(vs + (size_t)row * vstr + sc, (char*)vb + L);
  }
}

__device__ __forceinline__ void attn_tile(const short* kb, const short* vb,
                                          const short8 qf[2],
                                          float& m_run, float& l_run,
                                          f32x4 o_acc[4], int lane) {
  const int lr = lane & 15, hi = lane >> 4;
  f32x4 s[4];
#pragma unroll
  for (int nf = 0; nf < 4; ++nf) {
    int row = nf * 16 + lr;
    int rx = (row & 7) << 4;
    const char* base = (const char*)kb + row * 128;
    short8 k0 = *(const short8*)(base + ((hi * 16) ^ rx));
    short8 k1 = *(const short8*)(base + ((64 + hi * 16) ^ rx));
    f32x4 a = {0.f, 0.f, 0.f, 0.f};
    a = MFMA16(k0, qf[0], a);
    a = MFMA16(k1, qf[1], a);
    s[nf] = a;
  }
  float mx = fmaxf(fmaxf(s[0][0], s[0][1]), fmaxf(s[0][2], s[0][3]));
#pragma unroll
  for (int nf = 1; nf < 4; ++nf)
    mx = fmaxf(mx, fmaxf(fmaxf(s[nf][0], s[nf][1]), fmaxf(s[nf][2], s[nf][3])));
  if (__any(mx - m_run > 8.0f)) {
    float mr = fmaxf(mx, __shfl_xor(mx, 16));
    mr = fmaxf(mr, __shfl_xor(mr, 32));
    float mn = fmaxf(m_run, mr);
    float corr = __builtin_amdgcn_exp2f(m_run - mn);
    m_run = mn;
    l_run *= corr;
#pragma unroll
    for (int r = 0; r < 4; ++r) {
      float cr = __shfl(corr, hi * 4 + r);
#pragma unroll
      for (int no = 0; no < 4; ++no) o_acc[no][r] *= cr;
    }
  }
  short8 pa[2];
#pragma unroll
  for (int nf = 0; nf < 4; ++nf) {
#pragma unroll
    for (int r = 0; r < 4; ++r) {
      float p = __builtin_amdgcn_exp2f(s[nf][r] - m_run);
      l_run += p;
      pa[nf >> 1][(nf & 1) * 4 + r] = f2bf_trunc(p);
    }
  }
#pragma unroll
  for (int ks = 0; ks < 2; ++ks) {
#pragma unroll
    for (int no = 0; no < 4; ++no) {
      int row = no * 16 + lr;
      int rx = (row & 7) << 4;
      short8 vf = *(const short8*)((const char*)vb + row * 128 +
                                   ((ks * 64 + hi * 16) ^ rx));
      o_acc[no] = MFMA16(pa[ks], vf, o_acc[no]);
    }
  }
}

__global__ __launch_bounds__(256, 3) void attn_kernel(
    const short* __restrict__ qbuf, const short* __restrict__ kbuf,
    const short* __restrict__ vtbuf, const short* __restrict__ kipbuf,
    const short* __restrict__ vtipbuf, short* __restrict__ attn_out) {
  const int tid = threadIdx.x;
  const int lane = tid & 63, wid = tid >> 6;
  const int f = (blockIdx.x & 7) * 384 + (blockIdx.x >> 3);
  const int qt = f & 31;
  const int h = (f >> 5) % 24;
  const int b = f / (32 * 24);
  const int kvh = h >> 1;
  const int lr = lane & 15, hi = lane >> 4;

  __shared__ short skv_k[3 * 64 * 64];
  __shared__ short skv_v[3 * 64 * 64];

  const short* qp = qbuf + (size_t)(b * 24 + h) * 2048 * 64;
  const short* kp = kbuf + (size_t)(b * 12 + kvh) * 512 * 64;
  const short* vp = vtbuf + (size_t)(b * 12 + kvh) * 64 * 512;
  const short* kip = kipbuf + (size_t)(b * 12 + kvh) * 64 * 64;
  const short* vip = vtipbuf + (size_t)(b * 12 + kvh) * 64 * 64;

  const int q0 = qt * 64 + wid * 16;
  short8 qf[2];
  qf[0] = *(const short8*)(qp + (size_t)(q0 + lr) * 64 + hi * 8);
  qf[1] = *(const short8*)(qp + (size_t)(q0 + lr) * 64 + 32 + hi * 8);

  float m1 = -1.0e30f, l1 = 0.f, m2 = -1.0e30f, l2 = 0.f;
  f32x4 oacc1[4] = {}, oacc2[4] = {};

  stage_tile(kp, vp, 512, skv_k, skv_v, tid);
  stage_tile(kp + 64 * 64, vp + 64, 512, skv_k + 4096, skv_v + 4096, tid);
  asm volatile("s_waitcnt vmcnt(4)" ::: "memory");
  __builtin_amdgcn_s_barrier();

  for (int t = 0; t < 9; ++t) {
    if (t + 2 <= 8) {
      int tt = t + 2;
      const short* ks_ = (tt < 8) ? kp + tt * 64 * 64 : kip;
      const short* vs_ = (tt < 8) ? vp + tt * 64 : vip;
      int vstr = (tt < 8) ? 512 : 64;
      int bsel = tt % 3;
      stage_tile(ks_, vs_, vstr, skv_k + bsel * 4096, skv_v + bsel * 4096, tid);
    }
    __builtin_amdgcn_sched_barrier(0);
    int cur = t % 3;
    if (t < 8)
      attn_tile(skv_k + cur * 4096, skv_v + cur * 4096, qf, m1, l1, oacc1, lane);
    else
      attn_tile(skv_k + cur * 4096, skv_v + cur * 4096, qf, m2, l2, oacc2, lane);
    __builtin_amdgcn_sched_barrier(0);
    if (t + 2 <= 8)
      asm volatile("s_waitcnt vmcnt(4)" ::: "memory");
    else if (t + 1 <= 8)
      asm volatile("s_waitcnt vmcnt(0)" ::: "memory");
    __builtin_amdgcn_s_barrier();
  }

  l1 += __shfl_xor(l1, 16); l1 += __shfl_xor(l1, 32);
  l2 += __shfl_xor(l2, 16); l2 += __shfl_xor(l2, 32);
  float inv1 = 1.0f / l1, inv2 = 1.0f / l2;
#pragma unroll
  for (int r = 0; r < 4; ++r) {
    float i1 = __shfl(inv1, hi * 4 + r);
    float i2 = __shfl(inv2, hi * 4 + r);
    int grow = b * 2048 + q0 + hi * 4 + r;
#pragma unroll
    for (int no = 0; no < 4; ++no) {
      float val = oacc1[no][r] * i1 + oacc2[no][r] * i2;
      attn_out[(size_t)grow * 1536 + h * 64 + no * 16 + lr] = f2bf(val);
    }
  }
}

// ---------------------------------------------------------------------------
extern "C" void kernel_launch(void* const* d_in, const int* in_sizes, int n_in,
                              void* d_out, int out_size, void* d_ws, size_t ws_size,
                              hipStream_t stream) {
  const float* hs = (const float*)d_in[0];
  const float* enc = (const float*)d_in[1];
  const float* rc = (const float*)d_in[2];
  const float* rsn = (const float*)d_in[3];
  const float* wq = (const float*)d_in[4];
  const float* wk = (const float*)d_in[5];
  const float* wv = (const float*)d_in[6];
  const float* wkip = (const float*)d_in[7];
  const float* wvip = (const float*)d_in[8];
  const float* wo = (const float*)d_in[9];
  const float* bo = (const float*)d_in[10];
  float* out = (float*)d_out;

  char* ws = (char*)d_ws;
  short* attnbuf = (short*)(ws + 0);          // 25165824
  short* qbuf    = (short*)(ws + 25165824);   // 25165824
  short* kbuf    = (short*)(ws + 50331648);   //  3145728
  short* vtbuf   = (short*)(ws + 53477376);   //  3145728
  short* kipbuf  = (short*)(ws + 56623104);   //   393216
  short* vtipbuf = (short*)(ws + 57016320);   //   393216
  short* textbf  = (short*)(ws + 57409536);   //  3145728
  short* ipbf    = (short*)(ws + 60555264);   //   393216
  short* wqT     = (short*)(ws + 60948480);   //  4718592
  short* woT     = (short*)(ws + 65667072);   //  4718592
  short* wkvT    = (short*)(ws + 70385664);   //  2359296
  short* wkvipT  = (short*)(ws + 72744960);   //  2359296
  // total 75104256 bytes

  // --- fused pre-pass: enc pack + all weight transposes ---
  prepass_kernel<<<8640, 256, 0, stream>>>(enc, textbf, ipbf, wq, wo, wk, wv,
                                           wkip, wvip, wqT, woT, wkvT, wkvipT);

  // --- fused Q projection + K/V projections (q blocks first) ---
  qkv_kernel<<<984, 256, 0, stream>>>(hs, wqT, rc, rsn, qbuf, textbf, ipbf,
                                      wkvT, wkvipT, kbuf, vtbuf, kipbuf,
                                      vtipbuf);

  // --- attention ---
  attn_kernel<<<3072, 256, 0, stream>>>(qbuf, kbuf, vtbuf, kipbuf,
                                        vtipbuf, attnbuf);

  // --- output projection + bias + residual ---
  o_proj_128p<<<768, 256, 0, stream>>>(attnbuf, woT, bo, hs, out);
}